// Round 4
// baseline (9856.472 us; speedup 1.0000x reference)
//
#include <hip/hip_runtime.h>
#include <hip/hip_bf16.h>

// GNNRecommender: LSTM(20) + content linear + 2x bipartite SAGE + classifier.
// Round 4: self-verifying MFMA LSTM. k_mfma_trial computes a 32x512 gate tile via
// MFMA; k_mfma_check compares vs scalar recompute and clears flag_mfma on mismatch.
// LSTM steps branch: (isbf && mfma_ok) ? MFMA GEMM : round-3 VALU GEMM (proven).
// Downstream (scatter/sage/cls) identical to round-3 passing version.

typedef __bf16 bf16;
typedef __bf16 bf16x8 __attribute__((ext_vector_type(8)));
typedef float floatx4 __attribute__((ext_vector_type(4)));

#define N_NODES 32768
#define NMASK 32767
#define T_STEPS 20
#define EMBD 64
#define HD 128
#define G4 512   // 4*H gate width

__device__ __forceinline__ float sigf(float x) { return 1.f / (1.f + __expf(-x)); }

__device__ __forceinline__ float ldf(const void* p, size_t i, int isbf) {
  return isbf ? (float)((const bf16*)p)[i] : ((const float*)p)[i];
}

// ---------------- dtype probe: flag=1 bf16, 0 fp32; flag_mfma init to 1 ----------
__global__ void k_detect(const unsigned* __restrict__ x, int* __restrict__ flag,
                         int* __restrict__ flag_mfma)
{
  if (threadIdx.x == 0 && blockIdx.x == 0) {
    int cnt = 0;
    for (int i = 0; i < 256; ++i) {
      const unsigned w = x[i];
      const unsigned e0 = (w >> 7) & 0xffu;
      const unsigned e1 = (w >> 23) & 0xffu;
      const bool ok0 = (e0 >= 90u && e0 <= 141u) || ((w & 0x7fffu) == 0u);
      const bool ok1 = (e1 >= 90u && e1 <= 141u) || (((w >> 16) & 0x7fffu) == 0u);
      if (ok0 && ok1) ++cnt;
    }
    *flag = (cnt >= 200) ? 1 : 0;
    *flag_mfma = 1;
  }
}

// ---------------- zero-fill ----------------
__global__ __launch_bounds__(256) void k_zero(float4* __restrict__ p, int n4)
{
  const int i = blockIdx.x * 256 + threadIdx.x;
  if (i < n4) p[i] = float4{0.f, 0.f, 0.f, 0.f};
}

// ---------------- MFMA trial: gates(t=0, nodes 0..31) = x0 @ Wih^T, to scratch ----
__global__ __launch_bounds__(256) void k_mfma_trial(
    const void* __restrict__ x_user, const void* __restrict__ W_ih,
    float* __restrict__ trial, const int* __restrict__ flagp)
{
  if (!*flagp) return;                      // fp32 data: check will clear flag
  const bf16* xu = (const bf16*)x_user;
  const bf16* Wi = (const bf16*)W_ih;
  const int tid = threadIdx.x;
  const int wave = tid >> 6, lane = tid & 63;
  const int mrow = lane & 15, quad = lane >> 4;
  const int colbase = wave * 128;
  const floatx4 vzero = {0.f, 0.f, 0.f, 0.f};
  floatx4 acc[2][8];
  #pragma unroll
  for (int r = 0; r < 2; ++r)
    #pragma unroll
    for (int c = 0; c < 8; ++c) acc[r][c] = vzero;
  #pragma unroll
  for (int kc = 0; kc < 2; ++kc) {
    const int koff = kc * 32 + quad * 8;
    bf16x8 a[2];
    #pragma unroll
    for (int r = 0; r < 2; ++r)
      a[r] = *(const bf16x8*)(xu + (size_t)(r * 16 + mrow) * (T_STEPS * EMBD) + koff);
    #pragma unroll
    for (int ct = 0; ct < 8; ++ct) {
      const int g = colbase + ct * 16 + mrow;
      bf16x8 b = *(const bf16x8*)(Wi + (size_t)g * EMBD + koff);
      #pragma unroll
      for (int r = 0; r < 2; ++r)
        acc[r][ct] = __builtin_amdgcn_mfma_f32_16x16x32_bf16(a[r], b, acc[r][ct], 0, 0, 0);
    }
  }
  #pragma unroll
  for (int r = 0; r < 2; ++r)
    #pragma unroll
    for (int ct = 0; ct < 8; ++ct) {
      const int g = colbase + ct * 16 + mrow;
      #pragma unroll
      for (int reg = 0; reg < 4; ++reg)
        trial[(r * 16 + quad * 4 + reg) * G4 + g] = acc[r][ct][reg];
    }
}

// ---------------- MFMA check: scalar recompute nodes 0..3, all 512 cols ----------
__global__ __launch_bounds__(256) void k_mfma_check(
    const void* __restrict__ x_user, const void* __restrict__ W_ih,
    const float* __restrict__ trial, const int* __restrict__ flagp,
    int* __restrict__ flag_mfma)
{
  if (!*flagp) { if (threadIdx.x == 0) atomicAnd(flag_mfma, 0); return; }
  const bf16* xu = (const bf16*)x_user;
  const bf16* Wi = (const bf16*)W_ih;
  int ok = 1;
  #pragma unroll
  for (int cc = 0; cc < 2; ++cc) {
    const int col = threadIdx.x + cc * 256;
    for (int n = 0; n < 4; ++n) {
      float s = 0.f;
      for (int k = 0; k < EMBD; ++k)
        s += (float)xu[(size_t)n * (T_STEPS * EMBD) + k] * (float)Wi[(size_t)col * EMBD + k];
      const float d = fabsf(s - trial[n * G4 + col]);
      if (!(d < 5e-3f)) ok = 0;             // NaN-safe: NaN -> not ok
    }
  }
  if (!ok) atomicAnd(flag_mfma, 0);
}

// ---------------- LSTM step: MFMA or VALU GEMM + shared cell update ----------------
// 32 nodes/block, 256 threads. gates LDS layout: gates[node*G4 + col].
__global__ __launch_bounds__(256) void k_lstm_step(
    const void* __restrict__ x_user, const void* __restrict__ W_ih,
    const void* __restrict__ W_hh, const void* __restrict__ b_ih,
    const void* __restrict__ b_hh,
    bf16* __restrict__ h_bf, float* __restrict__ cstate, float* __restrict__ uOut,
    const int* __restrict__ flagp, const int* __restrict__ mfmap, int t)
{
  __shared__ float smem[32 * G4];           // 64 KB
  const int isbf = *flagp;
  const int use_mfma = isbf && (*mfmap);
  const int tid = threadIdx.x;
  const int n0 = blockIdx.x * 32;
  float* gates = smem;

  if (use_mfma) {
    const bf16* xu = (const bf16*)x_user;
    const bf16* Wi = (const bf16*)W_ih;
    const bf16* Wh = (const bf16*)W_hh;
    const int wave = tid >> 6, lane = tid & 63;
    const int mrow = lane & 15, quad = lane >> 4;
    const int colbase = wave * 128;
    const floatx4 vzero = {0.f, 0.f, 0.f, 0.f};
    floatx4 acc[2][8];
    #pragma unroll
    for (int r = 0; r < 2; ++r)
      #pragma unroll
      for (int c = 0; c < 8; ++c) acc[r][c] = vzero;

    // x_t @ W_ih^T  (K=64)
    #pragma unroll
    for (int kc = 0; kc < 2; ++kc) {
      const int koff = kc * 32 + quad * 8;
      bf16x8 a[2];
      #pragma unroll
      for (int r = 0; r < 2; ++r)
        a[r] = *(const bf16x8*)(xu +
                 (size_t)(n0 + r * 16 + mrow) * (T_STEPS * EMBD) + (size_t)t * EMBD + koff);
      #pragma unroll
      for (int ct = 0; ct < 8; ++ct) {
        const int g = colbase + ct * 16 + mrow;
        bf16x8 b = *(const bf16x8*)(Wi + (size_t)g * EMBD + koff);
        #pragma unroll
        for (int r = 0; r < 2; ++r)
          acc[r][ct] = __builtin_amdgcn_mfma_f32_16x16x32_bf16(a[r], b, acc[r][ct], 0, 0, 0);
      }
    }
    // h_{t-1} @ W_hh^T  (K=128)
    if (t > 0) {
      #pragma unroll
      for (int kc = 0; kc < 4; ++kc) {
        const int koff = kc * 32 + quad * 8;
        bf16x8 a[2];
        #pragma unroll
        for (int r = 0; r < 2; ++r)
          a[r] = *(const bf16x8*)(h_bf + (size_t)(n0 + r * 16 + mrow) * HD + koff);
        #pragma unroll
        for (int ct = 0; ct < 8; ++ct) {
          const int g = colbase + ct * 16 + mrow;
          bf16x8 b = *(const bf16x8*)(Wh + (size_t)g * HD + koff);
          #pragma unroll
          for (int r = 0; r < 2; ++r)
            acc[r][ct] = __builtin_amdgcn_mfma_f32_16x16x32_bf16(a[r], b, acc[r][ct], 0, 0, 0);
        }
      }
    }
    #pragma unroll
    for (int r = 0; r < 2; ++r)
      #pragma unroll
      for (int ct = 0; ct < 8; ++ct) {
        const int g = colbase + ct * 16 + mrow;
        const int nl = r * 16 + quad * 4;
        #pragma unroll
        for (int reg = 0; reg < 4; ++reg)
          gates[(nl + reg) * G4 + g] = acc[r][ct][reg];
      }
    __syncthreads();
  } else {
    // -------- round-3 VALU GEMM (proven) --------
    float* xl = smem;                        // 32x64
    float* hl = smem + 32 * EMBD;            // 32x128
    #pragma unroll
    for (int i = 0; i < 8; ++i) {
      const int idx = tid + i * 256;
      const int n = idx >> 6, k = idx & 63;
      xl[idx] = ldf(x_user, (size_t)(n0 + n) * (T_STEPS * EMBD) + (size_t)t * EMBD + k, isbf);
    }
    #pragma unroll
    for (int i = 0; i < 16; ++i) {
      const int idx = tid + i * 256;
      hl[idx] = (t == 0) ? 0.f : (float)h_bf[(size_t)n0 * HD + idx];
    }
    __syncthreads();
    const int col0 = tid, col1 = tid + 256;
    float acc0[32], acc1[32];
    #pragma unroll
    for (int n = 0; n < 32; ++n) { acc0[n] = 0.f; acc1[n] = 0.f; }
    for (int k = 0; k < EMBD; ++k) {
      const float w0 = ldf(W_ih, (size_t)col0 * EMBD + k, isbf);
      const float w1 = ldf(W_ih, (size_t)col1 * EMBD + k, isbf);
      #pragma unroll
      for (int n = 0; n < 32; ++n) {
        const float a = xl[n * EMBD + k];
        acc0[n] += a * w0; acc1[n] += a * w1;
      }
    }
    if (t > 0) {
      for (int k = 0; k < HD; ++k) {
        const float w0 = ldf(W_hh, (size_t)col0 * HD + k, isbf);
        const float w1 = ldf(W_hh, (size_t)col1 * HD + k, isbf);
        #pragma unroll
        for (int n = 0; n < 32; ++n) {
          const float a = hl[n * HD + k];
          acc0[n] += a * w0; acc1[n] += a * w1;
        }
      }
    }
    __syncthreads();
    #pragma unroll
    for (int n = 0; n < 32; ++n) {
      gates[n * G4 + col0] = acc0[n];
      gates[n * G4 + col1] = acc1[n];
    }
    __syncthreads();
  }

  // ---- cell update: 32 nodes x 128, 16/thread (gate order i,f,g,o) ----
  #pragma unroll
  for (int it = 0; it < 16; ++it) {
    const int lin = it * 256 + tid;
    const int nl = lin >> 7, j = lin & 127;
    const size_t n = (size_t)(n0 + nl);
    const float gi = gates[nl * G4 + j]       + ldf(b_ih, j, isbf)       + ldf(b_hh, j, isbf);
    const float gf = gates[nl * G4 + 128 + j] + ldf(b_ih, 128 + j, isbf) + ldf(b_hh, 128 + j, isbf);
    const float gg = gates[nl * G4 + 256 + j] + ldf(b_ih, 256 + j, isbf) + ldf(b_hh, 256 + j, isbf);
    const float go = gates[nl * G4 + 384 + j] + ldf(b_ih, 384 + j, isbf) + ldf(b_hh, 384 + j, isbf);
    const float iv = sigf(gi), fv = sigf(gf), gv = tanhf(gg), ov = sigf(go);
    const float cold = (t == 0) ? 0.f : cstate[n * HD + j];
    const float cnew = fv * cold + iv * gv;
    cstate[n * HD + j] = cnew;
    const float h = ov * tanhf(cnew);
    h_bf[n * HD + j] = (bf16)h;
    if (t == T_STEPS - 1) uOut[n * HD + j] = h;
  }
}

// ---------------- content linear ----------------
__global__ __launch_bounds__(256) void k_content(
    const void* __restrict__ x_content, const void* __restrict__ Wc,
    const void* __restrict__ bc, float* __restrict__ c_out,
    const int* __restrict__ flagp)
{
  __shared__ float xl[32 * EMBD];
  const int isbf = *flagp;
  const int tid = threadIdx.x;
  const int n0 = blockIdx.x * 32;
  #pragma unroll
  for (int i = 0; i < 8; ++i) {
    const int idx = tid + i * 256;
    xl[idx] = ldf(x_content, (size_t)n0 * EMBD + idx, isbf);
  }
  __syncthreads();
  const int jj = tid & 127, grp = tid >> 7;
  float acc[16];
  #pragma unroll
  for (int nn = 0; nn < 16; ++nn) acc[nn] = 0.f;
  for (int k = 0; k < EMBD; ++k) {
    const float w = ldf(Wc, (size_t)jj * EMBD + k, isbf);
    #pragma unroll
    for (int nn = 0; nn < 16; ++nn)
      acc[nn] += xl[(grp * 16 + nn) * EMBD + k] * w;
  }
  const float bj = ldf(bc, jj, isbf);
  #pragma unroll
  for (int nn = 0; nn < 16; ++nn)
    c_out[(size_t)(n0 + grp * 16 + nn) * HD + jj] = acc[nn] + bj;
}

// ---------------- degree counts ----------------
__global__ void k_count(const int* __restrict__ src, const int* __restrict__ dst,
                        float* __restrict__ cnt_u, float* __restrict__ cnt_c, int E)
{
  const int e = blockIdx.x * blockDim.x + threadIdx.x;
  if (e < E) {
    atomicAdd(cnt_u + (src[e] & NMASK), 1.f);
    atomicAdd(cnt_c + (dst[e] & NMASK), 1.f);
  }
}

// ---------------- scatter-add ----------------
__global__ __launch_bounds__(256) void k_scatter(
    const float* __restrict__ feat, const int* __restrict__ gidx,
    const int* __restrict__ sidx, float* __restrict__ agg, int E)
{
  const long long total = (long long)E * HD;
  const long long stride = (long long)gridDim.x * 256;
  for (long long i = (long long)blockIdx.x * 256 + threadIdx.x; i < total; i += stride) {
    const int e = (int)(i >> 7), j = (int)(i & 127);
    const int s = gidx[e] & NMASK, d = sidx[e] & NMASK;
    atomicAdd(agg + (size_t)d * HD + j, feat[(size_t)s * HD + j]);
  }
}

// ---------------- SAGE linear ----------------
__global__ __launch_bounds__(256) void k_sage_lin(
    const float* __restrict__ agg, const float* __restrict__ cnt,
    const float* __restrict__ dstx,
    const void* __restrict__ Wl, const void* __restrict__ bl,
    const void* __restrict__ Wr, float* __restrict__ outp,
    const int* __restrict__ flagp)
{
  __shared__ float ml[32 * HD];
  __shared__ float xl[32 * HD];
  const int isbf = *flagp;
  const int tid = threadIdx.x;
  const int n0 = blockIdx.x * 32;
  #pragma unroll
  for (int i = 0; i < 16; ++i) {
    const int idx = tid + i * 256;
    const int n = idx >> 7;
    const float rc = 1.f / fmaxf(cnt[n0 + n], 1.f);
    ml[idx] = agg[(size_t)n0 * HD + idx] * rc;
    xl[idx] = dstx[(size_t)n0 * HD + idx];
  }
  __syncthreads();
  const int jj = tid & 127, grp = tid >> 7;
  float acc[16];
  #pragma unroll
  for (int nn = 0; nn < 16; ++nn) acc[nn] = 0.f;
  for (int k = 0; k < HD; ++k) {
    const float wl = ldf(Wl, (size_t)jj * HD + k, isbf);
    const float wr = ldf(Wr, (size_t)jj * HD + k, isbf);
    #pragma unroll
    for (int nn = 0; nn < 16; ++nn)
      acc[nn] += ml[(grp * 16 + nn) * HD + k] * wl + xl[(grp * 16 + nn) * HD + k] * wr;
  }
  const float bj = ldf(bl, jj, isbf);
  #pragma unroll
  for (int nn = 0; nn < 16; ++nn)
    outp[(size_t)(n0 + grp * 16 + nn) * HD + jj] = fmaxf(acc[nn] + bj, 0.f);
}

// ---------------- classifier hidden ----------------
__global__ __launch_bounds__(256) void k_cls(
    const float* __restrict__ u, const float* __restrict__ c,
    const void* __restrict__ W1, const void* __restrict__ b1,
    float* __restrict__ h1, const int* __restrict__ flagp)
{
  __shared__ float ul[32 * HD];
  __shared__ float cl[32 * HD];
  const int isbf = *flagp;
  const int tid = threadIdx.x;
  const int n0 = blockIdx.x * 32;
  #pragma unroll
  for (int i = 0; i < 16; ++i) {
    const int idx = tid + i * 256;
    ul[idx] = u[(size_t)n0 * HD + idx];
    cl[idx] = c[(size_t)n0 * HD + idx];
  }
  __syncthreads();
  const int jj = tid & 127, grp = tid >> 7;
  float acc[16];
  #pragma unroll
  for (int nn = 0; nn < 16; ++nn) acc[nn] = 0.f;
  for (int k = 0; k < HD; ++k) {
    const float wu = ldf(W1, (size_t)jj * 256 + k, isbf);
    const float wc = ldf(W1, (size_t)jj * 256 + 128 + k, isbf);
    #pragma unroll
    for (int nn = 0; nn < 16; ++nn)
      acc[nn] += ul[(grp * 16 + nn) * HD + k] * wu + cl[(grp * 16 + nn) * HD + k] * wc;
  }
  const float bj = ldf(b1, jj, isbf);
  #pragma unroll
  for (int nn = 0; nn < 16; ++nn)
    h1[(size_t)(n0 + grp * 16 + nn) * HD + jj] = fmaxf(acc[nn] + bj, 0.f);
}

// ---------------- output ----------------
__global__ __launch_bounds__(256) void k_out(
    const float* __restrict__ h1, const void* __restrict__ W2,
    const void* __restrict__ b2, void* __restrict__ out,
    const int* __restrict__ flagp)
{
  const int isbf = *flagp;
  const int wave = threadIdx.x >> 6, lane = threadIdx.x & 63;
  const int n = blockIdx.x * 4 + wave;
  float v = h1[(size_t)n * HD + lane] * ldf(W2, lane, isbf)
          + h1[(size_t)n * HD + 64 + lane] * ldf(W2, 64 + lane, isbf);
  #pragma unroll
  for (int off = 32; off > 0; off >>= 1) v += __shfl_down(v, off, 64);
  if (lane == 0) {
    const float r = sigf(v + ldf(b2, 0, isbf));
    if (isbf) ((bf16*)out)[n] = (bf16)r; else ((float*)out)[n] = r;
  }
}

extern "C" void kernel_launch(void* const* d_in, const int* in_sizes, int n_in,
                              void* d_out, int out_size, void* d_ws, size_t ws_size,
                              hipStream_t stream)
{
  const void* x_user    = d_in[0];
  const void* x_content = d_in[1];
  const int*  edge      = (const int*)d_in[2];
  const void* W_ih      = d_in[3];
  const void* W_hh      = d_in[4];
  const void* b_ih      = d_in[5];
  const void* b_hh      = d_in[6];
  const void* Wc        = d_in[7];
  const void* bc        = d_in[8];
  const void* Wl[2]     = {d_in[9],  d_in[12]};
  const void* blv[2]    = {d_in[10], d_in[13]};
  const void* Wr[2]     = {d_in[11], d_in[14]};
  const void* W1        = d_in[15];
  const void* b1        = d_in[16];
  const void* W2        = d_in[17];
  const void* b2        = d_in[18];

  const int E = in_sizes[2] / 2;
  const int* src = edge;
  const int* dst = edge + E;

  // ---- workspace (~80.3 MB, proven budget). h_bf aliases u1; trial aliases c1 ----
  const size_t MB = 1u << 20;
  char* ws = (char*)d_ws;
  float* agg  = (float*)ws;                  // 16 MB: LSTM c-state -> agg -> h1
  float* cst  = agg;
  float* h1   = agg;
  float* u0 = (float*)(ws + 16 * MB);        // final u (fp32) + ping
  float* c0 = (float*)(ws + 32 * MB);
  float* u1 = (float*)(ws + 48 * MB);        // pong; first 8 MB alias h_bf
  float* c1 = (float*)(ws + 64 * MB);        // pong; first 64 KB alias trial
  bf16*  h_bf  = (bf16*)(ws + 48 * MB);      // LSTM h (bf16), dead before u1 written
  float* trial = (float*)(ws + 64 * MB);     // 64 KB, dead before c1 written
  float* cnt_c = (float*)(ws + 80 * MB);
  float* cnt_u = cnt_c + N_NODES;
  int*   flag      = (int*)(ws + 80 * MB + 512 * 1024);
  int*   flag_mfma = flag + 1;

  const int AGG4 = (int)(16 * MB / 16);
  const int CNT4 = (int)(2 * N_NODES * sizeof(float) / 16);

  // ---- probes ----
  k_detect<<<1, 64, 0, stream>>>((const unsigned*)x_user, flag, flag_mfma);
  k_mfma_trial<<<1, 256, 0, stream>>>(x_user, W_ih, trial, flag);
  k_mfma_check<<<1, 256, 0, stream>>>(x_user, W_ih, trial, flag, flag_mfma);

  // ---- LSTM 20 steps ----
  for (int t = 0; t < T_STEPS; ++t)
    k_lstm_step<<<N_NODES / 32, 256, 0, stream>>>(x_user, W_ih, W_hh, b_ih, b_hh,
                                                  h_bf, cst, u0, flag, flag_mfma, t);
  // ---- content embedding ----
  k_content<<<N_NODES / 32, 256, 0, stream>>>(x_content, Wc, bc, c0, flag);

  // ---- degree counts ----
  k_zero<<<(CNT4 + 255) / 256, 256, 0, stream>>>((float4*)cnt_c, CNT4);
  k_count<<<(E + 255) / 256, 256, 0, stream>>>(src, dst, cnt_u, cnt_c, E);

  // ---- 2 SAGE layers ----
  float* ui = u0; float* ci = c0; float* uo = u1; float* co = c1;
  for (int L = 0; L < 2; ++L) {
    k_zero<<<(AGG4 + 255) / 256, 256, 0, stream>>>((float4*)agg, AGG4);
    k_scatter<<<8192, 256, 0, stream>>>(ui, src, dst, agg, E);
    k_sage_lin<<<N_NODES / 32, 256, 0, stream>>>(agg, cnt_c, ci, Wl[L], blv[L], Wr[L], co, flag);
    k_zero<<<(AGG4 + 255) / 256, 256, 0, stream>>>((float4*)agg, AGG4);
    k_scatter<<<8192, 256, 0, stream>>>(ci, dst, src, agg, E);
    k_sage_lin<<<N_NODES / 32, 256, 0, stream>>>(agg, cnt_u, ui, Wl[L], blv[L], Wr[L], uo, flag);
    float* t1 = ui; ui = uo; uo = t1;
    float* t2 = ci; ci = co; co = t2;
  }

  // ---- classifier ----
  k_cls<<<N_NODES / 32, 256, 0, stream>>>(ui, ci, W1, b1, h1, flag);
  k_out<<<N_NODES / 4, 256, 0, stream>>>(h1, W2, b2, d_out, flag);
}

// Round 5
// 8546.732 us; speedup vs baseline: 1.1532x; 1.1532x over previous
//
#include <hip/hip_runtime.h>
#include <hip/hip_bf16.h>

// GNNRecommender: LSTM(20) + content linear + 2x bipartite SAGE + classifier.
// Round 5: (a) MFMA C/D layout measured on-device (LUT solver + verify, fallback
// to proven VALU GEMM); (b) atomic scatter replaced by CSR build + gather-sum.
// Internals bf16 (proven round 4, absmax 0.0), fp32 accumulation.

typedef __bf16 bf16;
typedef __bf16 bf16x2 __attribute__((ext_vector_type(2)));
typedef __bf16 bf16x8 __attribute__((ext_vector_type(8)));
typedef float floatx4 __attribute__((ext_vector_type(4)));

#define N_NODES 32768
#define NMASK 32767
#define T_STEPS 20
#define EMBD 64
#define HD 128
#define G4 512   // 4*H gate width

__device__ __forceinline__ float sigf(float x) { return 1.f / (1.f + __expf(-x)); }

__device__ __forceinline__ float ldf(const void* p, size_t i, int isbf) {
  return isbf ? (float)((const bf16*)p)[i] : ((const float*)p)[i];
}

// ---------------- dtype probe: flag=1 bf16, 0 fp32 ----------------
__global__ void k_detect(const unsigned* __restrict__ x, int* __restrict__ flag)
{
  if (threadIdx.x == 0 && blockIdx.x == 0) {
    int cnt = 0;
    for (int i = 0; i < 256; ++i) {
      const unsigned w = x[i];
      const unsigned e0 = (w >> 7) & 0xffu;
      const unsigned e1 = (w >> 23) & 0xffu;
      const bool ok0 = (e0 >= 90u && e0 <= 141u) || ((w & 0x7fffu) == 0u);
      const bool ok1 = (e1 >= 90u && e1 <= 141u) || (((w >> 16) & 0x7fffu) == 0u);
      if (ok0 && ok1) ++cnt;
    }
    *flag = (cnt >= 200) ? 1 : 0;
  }
}

// ---------------- zero int fill ----------------
__global__ __launch_bounds__(256) void k_zero_int(int* __restrict__ p, int n)
{
  const int i = blockIdx.x * 256 + threadIdx.x;
  if (i < n) p[i] = 0;
}

// ================= MFMA layout probe =================
// One wave computes two 16x16x32 MFMAs (same A, two distinct W k-panels).
// Raw per-(lane,reg) accumulators go to ws; the solver matches them against a
// scalar 16x16 reference to recover the true (lane,reg)->(m,n) mapping.
__global__ void k_trial(const void* __restrict__ x_user, const void* __restrict__ W_ih,
                        float* __restrict__ raw1, float* __restrict__ raw2,
                        const int* __restrict__ flagp)
{
  if (!*flagp) return;
  const bf16* xu = (const bf16*)x_user;
  const bf16* Wi = (const bf16*)W_ih;
  const int lane = threadIdx.x;
  if (lane >= 64) return;
  const int mrow = lane & 15, quad = lane >> 4;
  bf16x8 a1 = *(const bf16x8*)(xu + (size_t)mrow * (T_STEPS * EMBD) + quad * 8);
  bf16x8 a2 = *(const bf16x8*)(xu + (size_t)mrow * (T_STEPS * EMBD) + 32 + quad * 8);
  bf16x8 b1 = *(const bf16x8*)(Wi + (size_t)mrow * EMBD + quad * 8);
  bf16x8 b2 = *(const bf16x8*)(Wi + (size_t)mrow * EMBD + 32 + quad * 8);
  const floatx4 vz = {0.f, 0.f, 0.f, 0.f};
  floatx4 c1 = __builtin_amdgcn_mfma_f32_16x16x32_bf16(a1, b1, vz, 0, 0, 0);
  floatx4 c2 = __builtin_amdgcn_mfma_f32_16x16x32_bf16(a2, b2, vz, 0, 0, 0);
  #pragma unroll
  for (int reg = 0; reg < 4; ++reg) {
    raw1[lane * 4 + reg] = c1[reg];
    raw2[lane * 4 + reg] = c2[reg];
  }
}

// Solve mapping: thread tid owns raw index tid=(lane*4+reg). flag_mfma=1 iff all
// 256 entries match exactly one (m,n) in BOTH panels.
__global__ __launch_bounds__(256) void k_solve(
    const void* __restrict__ x_user, const void* __restrict__ W_ih,
    const float* __restrict__ raw1, const float* __restrict__ raw2,
    int* __restrict__ lut, int* __restrict__ flag_mfma)
{
  __shared__ float C1[256], C2[256];
  __shared__ int okcnt;
  const bf16* xu = (const bf16*)x_user;
  const bf16* Wi = (const bf16*)W_ih;
  const int tid = threadIdx.x;
  if (tid == 0) okcnt = 0;
  const int m = tid >> 4, n = tid & 15;
  float s1 = 0.f, s2 = 0.f;
  for (int k = 0; k < 32; ++k)
    s1 += (float)xu[(size_t)m * (T_STEPS * EMBD) + k] * (float)Wi[(size_t)n * EMBD + k];
  for (int k = 32; k < 64; ++k)
    s2 += (float)xu[(size_t)m * (T_STEPS * EMBD) + k] * (float)Wi[(size_t)n * EMBD + k];
  C1[tid] = s1; C2[tid] = s2;
  __syncthreads();
  const float r1 = raw1[tid], r2 = raw2[tid];
  int found = 0, cnt = 0;
  for (int mn = 0; mn < 256; ++mn) {
    const float d1 = fabsf(r1 - C1[mn]);
    const float d2 = fabsf(r2 - C2[mn]);
    if (d1 < 1e-4f && d2 < 1e-4f) { found = mn; ++cnt; }
  }
  lut[tid] = found;
  if (cnt == 1) atomicAdd(&okcnt, 1);
  __syncthreads();
  if (tid == 0) *flag_mfma = (okcnt == 256) ? 1 : 0;
}

// Trial2: run the REAL LSTM MFMA x@Wih path (t=0, nodes 0..15 tile) with LUT
// writes into trialg; k_verify scalar-checks it and clears flag_mfma on mismatch.
__global__ __launch_bounds__(256) void k_trial2(
    const void* __restrict__ x_user, const void* __restrict__ W_ih,
    const int* __restrict__ lut, float* __restrict__ trialg,
    const int* __restrict__ flag_mfma)
{
  if (!*flag_mfma) return;
  const bf16* xu = (const bf16*)x_user;
  const bf16* Wi = (const bf16*)W_ih;
  const int tid = threadIdx.x;
  const int wave = tid >> 6, lane = tid & 63;
  const int mrow = lane & 15, quad = lane >> 4;
  const int colbase = wave * 128;
  const floatx4 vz = {0.f, 0.f, 0.f, 0.f};
  floatx4 acc[8];
  #pragma unroll
  for (int c = 0; c < 8; ++c) acc[c] = vz;
  #pragma unroll
  for (int kc = 0; kc < 2; ++kc) {
    const int koff = kc * 32 + quad * 8;
    bf16x8 a = *(const bf16x8*)(xu + (size_t)mrow * (T_STEPS * EMBD) + koff);
    #pragma unroll
    for (int ct = 0; ct < 8; ++ct) {
      const int g = colbase + ct * 16 + mrow;
      bf16x8 b = *(const bf16x8*)(Wi + (size_t)g * EMBD + koff);
      acc[ct] = __builtin_amdgcn_mfma_f32_16x16x32_bf16(a, b, acc[ct], 0, 0, 0);
    }
  }
  int lm[4], ln[4];
  #pragma unroll
  for (int reg = 0; reg < 4; ++reg) {
    const int v = lut[lane * 4 + reg];
    lm[reg] = v >> 4; ln[reg] = v & 15;
  }
  #pragma unroll
  for (int ct = 0; ct < 8; ++ct)
    #pragma unroll
    for (int reg = 0; reg < 4; ++reg)
      trialg[lm[reg] * G4 + colbase + ct * 16 + ln[reg]] = acc[ct][reg];
}

__global__ __launch_bounds__(256) void k_verify(
    const void* __restrict__ x_user, const void* __restrict__ W_ih,
    const float* __restrict__ trialg, int* __restrict__ flag_mfma)
{
  if (!*flag_mfma) return;
  const bf16* xu = (const bf16*)x_user;
  const bf16* Wi = (const bf16*)W_ih;
  int ok = 1;
  #pragma unroll
  for (int cc = 0; cc < 2; ++cc) {
    const int col = threadIdx.x + cc * 256;
    for (int n = 0; n < 4; ++n) {
      float s = 0.f;
      for (int k = 0; k < EMBD; ++k)
        s += (float)xu[(size_t)n * (T_STEPS * EMBD) + k] * (float)Wi[(size_t)col * EMBD + k];
      const float d = fabsf(s - trialg[n * G4 + col]);
      if (!(d < 1e-4f)) ok = 0;
    }
  }
  if (!ok) atomicAnd(flag_mfma, 0);
}

// ================= LSTM step =================
__global__ __launch_bounds__(256) void k_lstm_step(
    const void* __restrict__ x_user, const void* __restrict__ W_ih,
    const void* __restrict__ W_hh, const void* __restrict__ b_ih,
    const void* __restrict__ b_hh,
    bf16* __restrict__ h_bf, float* __restrict__ cstate,
    const int* __restrict__ flagp, const int* __restrict__ mfmap,
    const int* __restrict__ lut, int t)
{
  __shared__ float smem[32 * G4];           // 64 KB
  const int isbf = *flagp;
  const int use_mfma = isbf && (*mfmap);
  const int tid = threadIdx.x;
  const int n0 = blockIdx.x * 32;
  float* gates = smem;

  if (use_mfma) {
    const bf16* xu = (const bf16*)x_user;
    const bf16* Wi = (const bf16*)W_ih;
    const bf16* Wh = (const bf16*)W_hh;
    const int wave = tid >> 6, lane = tid & 63;
    const int mrow = lane & 15, quad = lane >> 4;
    const int colbase = wave * 128;
    const floatx4 vz = {0.f, 0.f, 0.f, 0.f};
    floatx4 acc[2][8];
    #pragma unroll
    for (int r = 0; r < 2; ++r)
      #pragma unroll
      for (int c = 0; c < 8; ++c) acc[r][c] = vz;

    #pragma unroll
    for (int kc = 0; kc < 2; ++kc) {               // x_t @ W_ih^T (K=64)
      const int koff = kc * 32 + quad * 8;
      bf16x8 a[2];
      #pragma unroll
      for (int r = 0; r < 2; ++r)
        a[r] = *(const bf16x8*)(xu +
                 (size_t)(n0 + r * 16 + mrow) * (T_STEPS * EMBD) + (size_t)t * EMBD + koff);
      #pragma unroll
      for (int ct = 0; ct < 8; ++ct) {
        const int g = colbase + ct * 16 + mrow;
        bf16x8 b = *(const bf16x8*)(Wi + (size_t)g * EMBD + koff);
        #pragma unroll
        for (int r = 0; r < 2; ++r)
          acc[r][ct] = __builtin_amdgcn_mfma_f32_16x16x32_bf16(a[r], b, acc[r][ct], 0, 0, 0);
      }
    }
    if (t > 0) {                                   // h_{t-1} @ W_hh^T (K=128)
      #pragma unroll
      for (int kc = 0; kc < 4; ++kc) {
        const int koff = kc * 32 + quad * 8;
        bf16x8 a[2];
        #pragma unroll
        for (int r = 0; r < 2; ++r)
          a[r] = *(const bf16x8*)(h_bf + (size_t)(n0 + r * 16 + mrow) * HD + koff);
        #pragma unroll
        for (int ct = 0; ct < 8; ++ct) {
          const int g = colbase + ct * 16 + mrow;
          bf16x8 b = *(const bf16x8*)(Wh + (size_t)g * HD + koff);
          #pragma unroll
          for (int r = 0; r < 2; ++r)
            acc[r][ct] = __builtin_amdgcn_mfma_f32_16x16x32_bf16(a[r], b, acc[r][ct], 0, 0, 0);
        }
      }
    }
    int lm[4], ln[4];
    #pragma unroll
    for (int reg = 0; reg < 4; ++reg) {
      const int v = lut[lane * 4 + reg];
      lm[reg] = v >> 4; ln[reg] = v & 15;
    }
    #pragma unroll
    for (int r = 0; r < 2; ++r)
      #pragma unroll
      for (int ct = 0; ct < 8; ++ct)
        #pragma unroll
        for (int reg = 0; reg < 4; ++reg)
          gates[(r * 16 + lm[reg]) * G4 + colbase + ct * 16 + ln[reg]] = acc[r][ct][reg];
    __syncthreads();
  } else {
    // -------- proven VALU GEMM fallback --------
    float* xl = smem;                        // 32x64
    float* hl = smem + 32 * EMBD;            // 32x128
    #pragma unroll
    for (int i = 0; i < 8; ++i) {
      const int idx = tid + i * 256;
      const int n = idx >> 6, k = idx & 63;
      xl[idx] = ldf(x_user, (size_t)(n0 + n) * (T_STEPS * EMBD) + (size_t)t * EMBD + k, isbf);
    }
    #pragma unroll
    for (int i = 0; i < 16; ++i) {
      const int idx = tid + i * 256;
      hl[idx] = (t == 0) ? 0.f : (float)h_bf[(size_t)n0 * HD + idx];
    }
    __syncthreads();
    const int col0 = tid, col1 = tid + 256;
    float acc0[32], acc1[32];
    #pragma unroll
    for (int n = 0; n < 32; ++n) { acc0[n] = 0.f; acc1[n] = 0.f; }
    for (int k = 0; k < EMBD; ++k) {
      const float w0 = ldf(W_ih, (size_t)col0 * EMBD + k, isbf);
      const float w1 = ldf(W_ih, (size_t)col1 * EMBD + k, isbf);
      #pragma unroll
      for (int n = 0; n < 32; ++n) {
        const float a = xl[n * EMBD + k];
        acc0[n] += a * w0; acc1[n] += a * w1;
      }
    }
    if (t > 0) {
      for (int k = 0; k < HD; ++k) {
        const float w0 = ldf(W_hh, (size_t)col0 * HD + k, isbf);
        const float w1 = ldf(W_hh, (size_t)col1 * HD + k, isbf);
        #pragma unroll
        for (int n = 0; n < 32; ++n) {
          const float a = hl[n * HD + k];
          acc0[n] += a * w0; acc1[n] += a * w1;
        }
      }
    }
    __syncthreads();
    #pragma unroll
    for (int n = 0; n < 32; ++n) {
      gates[n * G4 + col0] = acc0[n];
      gates[n * G4 + col1] = acc1[n];
    }
    __syncthreads();
  }

  // ---- cell update (gate order i,f,g,o) ----
  #pragma unroll
  for (int it = 0; it < 16; ++it) {
    const int lin = it * 256 + tid;
    const int nl = lin >> 7, j = lin & 127;
    const size_t n = (size_t)(n0 + nl);
    const float gi = gates[nl * G4 + j]       + ldf(b_ih, j, isbf)       + ldf(b_hh, j, isbf);
    const float gf = gates[nl * G4 + 128 + j] + ldf(b_ih, 128 + j, isbf) + ldf(b_hh, 128 + j, isbf);
    const float gg = gates[nl * G4 + 256 + j] + ldf(b_ih, 256 + j, isbf) + ldf(b_hh, 256 + j, isbf);
    const float go = gates[nl * G4 + 384 + j] + ldf(b_ih, 384 + j, isbf) + ldf(b_hh, 384 + j, isbf);
    const float iv = sigf(gi), fv = sigf(gf), gv = tanhf(gg), ov = sigf(go);
    const float cold = (t == 0) ? 0.f : cstate[n * HD + j];
    const float cnew = fv * cold + iv * gv;
    cstate[n * HD + j] = cnew;
    h_bf[n * HD + j] = (bf16)(ov * tanhf(cnew));
  }
}

// ---------------- content linear ----------------
__global__ __launch_bounds__(256) void k_content(
    const void* __restrict__ x_content, const void* __restrict__ Wc,
    const void* __restrict__ bc, bf16* __restrict__ c_out,
    const int* __restrict__ flagp)
{
  __shared__ float xl[32 * EMBD];
  const int isbf = *flagp;
  const int tid = threadIdx.x;
  const int n0 = blockIdx.x * 32;
  #pragma unroll
  for (int i = 0; i < 8; ++i) {
    const int idx = tid + i * 256;
    xl[idx] = ldf(x_content, (size_t)n0 * EMBD + idx, isbf);
  }
  __syncthreads();
  const int jj = tid & 127, grp = tid >> 7;
  float acc[16];
  #pragma unroll
  for (int nn = 0; nn < 16; ++nn) acc[nn] = 0.f;
  for (int k = 0; k < EMBD; ++k) {
    const float w = ldf(Wc, (size_t)jj * EMBD + k, isbf);
    #pragma unroll
    for (int nn = 0; nn < 16; ++nn)
      acc[nn] += xl[(grp * 16 + nn) * EMBD + k] * w;
  }
  const float bj = ldf(bc, jj, isbf);
  #pragma unroll
  for (int nn = 0; nn < 16; ++nn)
    c_out[(size_t)(n0 + grp * 16 + nn) * HD + jj] = (bf16)(acc[nn] + bj);
}

// ================= CSR build =================
__global__ void k_count_int(const int* __restrict__ src, const int* __restrict__ dst,
                            int* __restrict__ deg_u, int* __restrict__ deg_c, int E)
{
  const int e = blockIdx.x * blockDim.x + threadIdx.x;
  if (e < E) {
    atomicAdd(deg_u + (src[e] & NMASK), 1);
    atomicAdd(deg_c + (dst[e] & NMASK), 1);
  }
}

// exclusive prefix over 32768 ints; writes row (32769) and cur (32768)
__global__ __launch_bounds__(256) void k_scan(const int* __restrict__ deg,
                                              int* __restrict__ row, int* __restrict__ cur)
{
  __shared__ int part[256];
  const int tid = threadIdx.x;
  const int base = tid * 128;
  int s = 0;
  for (int i = 0; i < 128; ++i) s += deg[base + i];
  part[tid] = s;
  __syncthreads();
  if (tid == 0) {
    int a = 0;
    for (int i = 0; i < 256; ++i) { const int v = part[i]; part[i] = a; a += v; }
  }
  __syncthreads();
  int a = part[tid];
  for (int i = 0; i < 128; ++i) {
    row[base + i] = a; cur[base + i] = a;
    a += deg[base + i];
  }
  if (tid == 255) row[N_NODES] = a;
}

__global__ void k_build(const int* __restrict__ src, const int* __restrict__ dst,
                        int* __restrict__ cur_u, int* __restrict__ cur_c,
                        int* __restrict__ adj_u, int* __restrict__ adj_c, int E)
{
  const int e = blockIdx.x * blockDim.x + threadIdx.x;
  if (e < E) {
    const int s = src[e] & NMASK, d = dst[e] & NMASK;
    const int pc = atomicAdd(cur_c + d, 1);
    adj_c[pc] = s;                      // neighbors (users) of content node d
    const int pu = atomicAdd(cur_u + s, 1);
    adj_u[pu] = d;                      // neighbors (contents) of user node s
  }
}

// gather-sum: agg[n][:] = sum over adj rows of feat. One wave per node.
__global__ __launch_bounds__(256) void k_gather(
    const bf16* __restrict__ feat, const int* __restrict__ adj,
    const int* __restrict__ row, float* __restrict__ agg)
{
  const int node = blockIdx.x * 4 + (threadIdx.x >> 6);
  const int lane = threadIdx.x & 63;
  const int beg = row[node], end = row[node + 1];
  float a0 = 0.f, a1 = 0.f;
  for (int p = beg; p < end; ++p) {
    const int s = adj[p];
    const bf16x2 v = *(const bf16x2*)(feat + (size_t)s * HD + 2 * lane);
    a0 += (float)v.x; a1 += (float)v.y;
  }
  float2* o = (float2*)(agg + (size_t)node * HD + 2 * lane);
  *o = float2{a0, a1};
}

// ---------------- SAGE linear ----------------
__global__ __launch_bounds__(256) void k_sage_lin(
    const float* __restrict__ agg, const int* __restrict__ cnt,
    const bf16* __restrict__ dstx,
    const void* __restrict__ Wl, const void* __restrict__ bl,
    const void* __restrict__ Wr, bf16* __restrict__ outp,
    const int* __restrict__ flagp)
{
  __shared__ float ml[32 * HD];
  __shared__ float xl[32 * HD];
  const int isbf = *flagp;
  const int tid = threadIdx.x;
  const int n0 = blockIdx.x * 32;
  #pragma unroll
  for (int i = 0; i < 16; ++i) {
    const int idx = tid + i * 256;
    const int n = idx >> 7;
    const float rc = 1.f / fmaxf((float)cnt[n0 + n], 1.f);
    ml[idx] = agg[(size_t)n0 * HD + idx] * rc;
    xl[idx] = (float)dstx[(size_t)n0 * HD + idx];
  }
  __syncthreads();
  const int jj = tid & 127, grp = tid >> 7;
  float acc[16];
  #pragma unroll
  for (int nn = 0; nn < 16; ++nn) acc[nn] = 0.f;
  for (int k = 0; k < HD; ++k) {
    const float wl = ldf(Wl, (size_t)jj * HD + k, isbf);
    const float wr = ldf(Wr, (size_t)jj * HD + k, isbf);
    #pragma unroll
    for (int nn = 0; nn < 16; ++nn)
      acc[nn] += ml[(grp * 16 + nn) * HD + k] * wl + xl[(grp * 16 + nn) * HD + k] * wr;
  }
  const float bj = ldf(bl, jj, isbf);
  #pragma unroll
  for (int nn = 0; nn < 16; ++nn)
    outp[(size_t)(n0 + grp * 16 + nn) * HD + jj] = (bf16)fmaxf(acc[nn] + bj, 0.f);
}

// ---------------- classifier hidden ----------------
__global__ __launch_bounds__(256) void k_cls(
    const bf16* __restrict__ u, const bf16* __restrict__ c,
    const void* __restrict__ W1, const void* __restrict__ b1,
    float* __restrict__ h1, const int* __restrict__ flagp)
{
  __shared__ float ul[32 * HD];
  __shared__ float cl[32 * HD];
  const int isbf = *flagp;
  const int tid = threadIdx.x;
  const int n0 = blockIdx.x * 32;
  #pragma unroll
  for (int i = 0; i < 16; ++i) {
    const int idx = tid + i * 256;
    ul[idx] = (float)u[(size_t)n0 * HD + idx];
    cl[idx] = (float)c[(size_t)n0 * HD + idx];
  }
  __syncthreads();
  const int jj = tid & 127, grp = tid >> 7;
  float acc[16];
  #pragma unroll
  for (int nn = 0; nn < 16; ++nn) acc[nn] = 0.f;
  for (int k = 0; k < HD; ++k) {
    const float wu = ldf(W1, (size_t)jj * 256 + k, isbf);
    const float wc = ldf(W1, (size_t)jj * 256 + 128 + k, isbf);
    #pragma unroll
    for (int nn = 0; nn < 16; ++nn)
      acc[nn] += ul[(grp * 16 + nn) * HD + k] * wu + cl[(grp * 16 + nn) * HD + k] * wc;
  }
  const float bj = ldf(b1, jj, isbf);
  #pragma unroll
  for (int nn = 0; nn < 16; ++nn)
    h1[(size_t)(n0 + grp * 16 + nn) * HD + jj] = fmaxf(acc[nn] + bj, 0.f);
}

// ---------------- output ----------------
__global__ __launch_bounds__(256) void k_out(
    const float* __restrict__ h1, const void* __restrict__ W2,
    const void* __restrict__ b2, void* __restrict__ out,
    const int* __restrict__ flagp)
{
  const int isbf = *flagp;
  const int wave = threadIdx.x >> 6, lane = threadIdx.x & 63;
  const int n = blockIdx.x * 4 + wave;
  float v = h1[(size_t)n * HD + lane] * ldf(W2, lane, isbf)
          + h1[(size_t)n * HD + 64 + lane] * ldf(W2, 64 + lane, isbf);
  #pragma unroll
  for (int off = 32; off > 0; off >>= 1) v += __shfl_down(v, off, 64);
  if (lane == 0) {
    const float r = sigf(v + ldf(b2, 0, isbf));
    if (isbf) ((bf16*)out)[n] = (bf16)r; else ((float*)out)[n] = r;
  }
}

extern "C" void kernel_launch(void* const* d_in, const int* in_sizes, int n_in,
                              void* d_out, int out_size, void* d_ws, size_t ws_size,
                              hipStream_t stream)
{
  const void* x_user    = d_in[0];
  const void* x_content = d_in[1];
  const int*  edge      = (const int*)d_in[2];
  const void* W_ih      = d_in[3];
  const void* W_hh      = d_in[4];
  const void* b_ih      = d_in[5];
  const void* b_hh      = d_in[6];
  const void* Wc        = d_in[7];
  const void* bc        = d_in[8];
  const void* Wl[2]     = {d_in[9],  d_in[12]};
  const void* blv[2]    = {d_in[10], d_in[13]};
  const void* Wr[2]     = {d_in[11], d_in[14]};
  const void* W1        = d_in[15];
  const void* b1        = d_in[16];
  const void* W2        = d_in[17];
  const void* b2        = d_in[18];

  const int E = in_sizes[2] / 2;
  const int* src = edge;
  const int* dst = edge + E;

  // ---- workspace layout (< 60 MB; 80.3 MB proven available) ----
  const size_t MB = 1u << 20;
  char* ws = (char*)d_ws;
  float* agg  = (float*)ws;                  // 16 MB fp32: cstate -> agg -> h1
  float* cst  = agg;
  float* h1   = agg;
  bf16* u0 = (bf16*)(ws + 16 * MB);          // 8 MB: LSTM h / u ping
  bf16* c0 = (bf16*)(ws + 24 * MB);          // 8 MB
  bf16* u1 = (bf16*)(ws + 32 * MB);          // 8 MB
  bf16* c1 = (bf16*)(ws + 40 * MB);          // 8 MB
  int*  adj_c = (int*)(ws + 48 * MB);        // 4 MB (E <= 1M)
  int*  adj_u = (int*)(ws + 52 * MB);        // 4 MB
  int*  meta  = (int*)(ws + 56 * MB);
  int* deg_u = meta;                         // 32768
  int* deg_c = deg_u + N_NODES;              // 32768 (contiguous with deg_u for zeroing)
  int* row_u = deg_c + N_NODES;              // 32769
  int* row_c = row_u + N_NODES + 1;          // 32769
  int* cur_u = row_c + N_NODES + 1;          // 32768
  int* cur_c = cur_u + N_NODES;              // 32768
  int* flag      = cur_c + N_NODES;
  int* flag_mfma = flag + 1;
  int* lut       = flag_mfma + 1;            // 256
  float* raw1    = (float*)(lut + 256);      // 256
  float* raw2    = raw1 + 256;               // 256
  float* trialg  = raw2 + 256;               // 32*512 fp32 = 64 KB

  // ---- dtype probe + MFMA layout solve/verify ----
  k_detect<<<1, 64, 0, stream>>>((const unsigned*)x_user, flag);
  k_trial<<<1, 64, 0, stream>>>(x_user, W_ih, raw1, raw2, flag);
  k_solve<<<1, 256, 0, stream>>>(x_user, W_ih, raw1, raw2, lut, flag_mfma);
  k_trial2<<<1, 256, 0, stream>>>(x_user, W_ih, lut, trialg, flag_mfma);
  k_verify<<<1, 256, 0, stream>>>(x_user, W_ih, trialg, flag_mfma);

  // ---- LSTM 20 steps ----
  for (int t = 0; t < T_STEPS; ++t)
    k_lstm_step<<<N_NODES / 32, 256, 0, stream>>>(x_user, W_ih, W_hh, b_ih, b_hh,
                                                  u0, cst, flag, flag_mfma, lut, t);
  // ---- content embedding ----
  k_content<<<N_NODES / 32, 256, 0, stream>>>(x_content, Wc, bc, c0, flag);

  // ---- CSR build (both directions) ----
  k_zero_int<<<(2 * N_NODES + 255) / 256, 256, 0, stream>>>(deg_u, 2 * N_NODES);
  k_count_int<<<(E + 255) / 256, 256, 0, stream>>>(src, dst, deg_u, deg_c, E);
  k_scan<<<1, 256, 0, stream>>>(deg_u, row_u, cur_u);
  k_scan<<<1, 256, 0, stream>>>(deg_c, row_c, cur_c);
  k_build<<<(E + 255) / 256, 256, 0, stream>>>(src, dst, cur_u, cur_c, adj_u, adj_c, E);

  // ---- 2 SAGE layers (both directions read OLD u,c) ----
  bf16* ui = u0; bf16* ci = c0; bf16* uo = u1; bf16* co = c1;
  for (int L = 0; L < 2; ++L) {
    k_gather<<<N_NODES / 4, 256, 0, stream>>>(ui, adj_c, row_c, agg);   // users -> content
    k_sage_lin<<<N_NODES / 32, 256, 0, stream>>>(agg, deg_c, ci, Wl[L], blv[L], Wr[L], co, flag);
    k_gather<<<N_NODES / 4, 256, 0, stream>>>(ci, adj_u, row_u, agg);   // content -> users
    k_sage_lin<<<N_NODES / 32, 256, 0, stream>>>(agg, deg_u, ui, Wl[L], blv[L], Wr[L], uo, flag);
    bf16* t1 = ui; ui = uo; uo = t1;
    bf16* t2 = ci; ci = co; co = t2;
  }

  // ---- classifier (h1 reuses agg region, agg dead) ----
  k_cls<<<N_NODES / 32, 256, 0, stream>>>(ui, ci, W1, b1, h1, flag);
  k_out<<<N_NODES / 4, 256, 0, stream>>>(h1, W2, b2, d_out, flag);
}

// Round 6
// 8527.845 us; speedup vs baseline: 1.1558x; 1.0022x over previous
//
#include <hip/hip_runtime.h>
#include <hip/hip_bf16.h>

// GNNRecommender: LSTM(20) + content linear + 2x bipartite SAGE (CSR gather) + classifier.
// Round 6: collision-proof on-device MFMA layout recovery with synthetic integer
// probes (no input-data dependence); hedge with 16x16x16bf16_1k; VALU fallback.

typedef __bf16 bf16;
typedef __bf16 bf16x2 __attribute__((ext_vector_type(2)));
typedef __bf16 bf16x8 __attribute__((ext_vector_type(8)));
typedef short short4v __attribute__((ext_vector_type(4)));
typedef float floatx4 __attribute__((ext_vector_type(4)));

#if __has_builtin(__builtin_amdgcn_mfma_f32_16x16x16bf16_1k)
#define HAVE16 1
#else
#define HAVE16 0
#endif

#define N_NODES 32768
#define NMASK 32767
#define T_STEPS 20
#define EMBD 64
#define HD 128
#define G4 512   // 4*H gate width

__device__ __forceinline__ float sigf(float x) { return 1.f / (1.f + __expf(-x)); }

__device__ __forceinline__ float ldf(const void* p, size_t i, int isbf) {
  return isbf ? (float)((const bf16*)p)[i] : ((const float*)p)[i];
}

// exact-integer probe matrices (values small => exact in bf16 and fp32)
__device__ __forceinline__ float A3f(int m, int k) { return (float)((m * 37 + k * 11) % 13 - 6); }
__device__ __forceinline__ float B3f(int k, int n) { return (float)((k * 7 + n * 29) % 11 - 5); }
__device__ __forceinline__ short bfb(float f) { return (short)(__float_as_uint(f) >> 16); }

// ---------------- dtype probe: flag=1 bf16, 0 fp32 ----------------
__global__ void k_detect(const unsigned* __restrict__ x, int* __restrict__ flag)
{
  if (threadIdx.x == 0 && blockIdx.x == 0) {
    int cnt = 0;
    for (int i = 0; i < 256; ++i) {
      const unsigned w = x[i];
      const unsigned e0 = (w >> 7) & 0xffu;
      const unsigned e1 = (w >> 23) & 0xffu;
      const bool ok0 = (e0 >= 90u && e0 <= 141u) || ((w & 0x7fffu) == 0u);
      const bool ok1 = (e1 >= 90u && e1 <= 141u) || (((w >> 16) & 0x7fffu) == 0u);
      if (ok0 && ok1) ++cnt;
    }
    *flag = (cnt >= 200) ? 1 : 0;
  }
}

__global__ __launch_bounds__(256) void k_zero_int(int* __restrict__ p, int n)
{
  const int i = blockIdx.x * 256 + threadIdx.x;
  if (i < n) p[i] = 0;
}

// ================= MFMA probe: synthetic, exact, collision-free =================
// Recovers (lane,reg)->(m,n) LUT for each variant; validates bijectivity and an
// exact pseudo-random product (catches k-map twists / broken lowering).
__global__ __launch_bounds__(64) void k_probe(int* __restrict__ lut32, int* __restrict__ ok32p,
                                              int* __restrict__ lut16, int* __restrict__ ok16p)
{
  __shared__ int seen[256];
  __shared__ int fail;
  const int lane = threadIdx.x;
  const int mrow = lane & 15, quad = lane >> 4;
  const floatx4 vz = {0.f, 0.f, 0.f, 0.f};

  // ---------- variant 1: v_mfma_f32_16x16x32_bf16 ----------
  for (int i = lane; i < 256; i += 64) seen[i] = 0;
  if (lane == 0) fail = 0;
  __syncthreads();
  {
    bf16x8 a1, b1, a2, b2, a3, b3;
    #pragma unroll
    for (int j = 0; j < 8; ++j) {
      a1[j] = (bf16)(float)(mrow + 1); b1[j] = (bf16)1.0f;
      a2[j] = (bf16)1.0f;              b2[j] = (bf16)(float)(mrow + 1);
      a3[j] = (bf16)A3f(mrow, quad * 8 + j);
      b3[j] = (bf16)B3f(quad * 8 + j, mrow);
    }
    floatx4 r1 = __builtin_amdgcn_mfma_f32_16x16x32_bf16(a1, b1, vz, 0, 0, 0);
    floatx4 r2 = __builtin_amdgcn_mfma_f32_16x16x32_bf16(a2, b2, vz, 0, 0, 0);
    floatx4 r3 = __builtin_amdgcn_mfma_f32_16x16x32_bf16(a3, b3, vz, 0, 0, 0);
    #pragma unroll
    for (int reg = 0; reg < 4; ++reg) {
      const int m = __float2int_rn(r1[reg] * (1.f / 32.f)) - 1;
      const int n = __float2int_rn(r2[reg] * (1.f / 32.f)) - 1;
      bool good = (m >= 0 && m < 16 && n >= 0 && n < 16)
               && fabsf(r1[reg] - 32.f * (m + 1)) < 0.5f
               && fabsf(r2[reg] - 32.f * (n + 1)) < 0.5f;
      if (good) {
        float c3 = 0.f;
        for (int k = 0; k < 32; ++k) c3 += A3f(m, k) * B3f(k, n);
        good = fabsf(r3[reg] - c3) < 0.5f;
      }
      if (good) {
        atomicAdd(&seen[m * 16 + n], 1);
        lut32[lane * 4 + reg] = (m << 4) | n;
      } else fail = 1;
    }
  }
  __syncthreads();
  {
    int bij = 1;
    for (int i = lane; i < 256; i += 64) if (seen[i] != 1) bij = 0;
    if (!bij) fail = 1;
  }
  __syncthreads();
  if (lane == 0) *ok32p = fail ? 0 : 1;
  __syncthreads();

  // ---------- variant 2: v_mfma_f32_16x16x16_bf16 (_1k builtin) ----------
  for (int i = lane; i < 256; i += 64) seen[i] = 0;
  if (lane == 0) fail = 0;
  __syncthreads();
#if HAVE16
  {
    short4v a1, b1, a2, b2, a3, b3;
    #pragma unroll
    for (int j = 0; j < 4; ++j) {
      a1[j] = bfb((float)(mrow + 1)); b1[j] = bfb(1.0f);
      a2[j] = bfb(1.0f);              b2[j] = bfb((float)(mrow + 1));
      a3[j] = bfb(A3f(mrow, quad * 4 + j));
      b3[j] = bfb(B3f(quad * 4 + j, mrow));
    }
    floatx4 r1 = __builtin_amdgcn_mfma_f32_16x16x16bf16_1k(a1, b1, vz, 0, 0, 0);
    floatx4 r2 = __builtin_amdgcn_mfma_f32_16x16x16bf16_1k(a2, b2, vz, 0, 0, 0);
    floatx4 r3 = __builtin_amdgcn_mfma_f32_16x16x16bf16_1k(a3, b3, vz, 0, 0, 0);
    #pragma unroll
    for (int reg = 0; reg < 4; ++reg) {
      const int m = __float2int_rn(r1[reg] * (1.f / 16.f)) - 1;
      const int n = __float2int_rn(r2[reg] * (1.f / 16.f)) - 1;
      bool good = (m >= 0 && m < 16 && n >= 0 && n < 16)
               && fabsf(r1[reg] - 16.f * (m + 1)) < 0.5f
               && fabsf(r2[reg] - 16.f * (n + 1)) < 0.5f;
      if (good) {
        float c3 = 0.f;
        for (int k = 0; k < 16; ++k) c3 += A3f(m, k) * B3f(k, n);
        good = fabsf(r3[reg] - c3) < 0.5f;
      }
      if (good) {
        atomicAdd(&seen[m * 16 + n], 1);
        lut16[lane * 4 + reg] = (m << 4) | n;
      } else fail = 1;
    }
  }
  __syncthreads();
  {
    int bij = 1;
    for (int i = lane; i < 256; i += 64) if (seen[i] != 1) bij = 0;
    if (!bij) fail = 1;
  }
  __syncthreads();
  if (lane == 0) *ok16p = fail ? 0 : 1;
#else
  if (lane == 0) *ok16p = 0;
#endif
}

// ================= LSTM step =================
__global__ __launch_bounds__(256) void k_lstm_step(
    const void* __restrict__ x_user, const void* __restrict__ W_ih,
    const void* __restrict__ W_hh, const void* __restrict__ b_ih,
    const void* __restrict__ b_hh,
    bf16* __restrict__ h_bf, float* __restrict__ cstate,
    const int* __restrict__ flagp, const int* __restrict__ ok32p,
    const int* __restrict__ ok16p, const int* __restrict__ lut32,
    const int* __restrict__ lut16, int t)
{
  __shared__ float smem[32 * G4];           // 64 KB
  const int isbf = *flagp;
  const int use32 = isbf && *ok32p;
  const int use16 = isbf && !use32 && *ok16p;
  const int tid = threadIdx.x;
  const int n0 = blockIdx.x * 32;
  float* gates = smem;

  if (use32) {
    const bf16* xu = (const bf16*)x_user;
    const bf16* Wi = (const bf16*)W_ih;
    const bf16* Wh = (const bf16*)W_hh;
    const int wave = tid >> 6, lane = tid & 63;
    const int mrow = lane & 15, quad = lane >> 4;
    const int colbase = wave * 128;
    const floatx4 vz = {0.f, 0.f, 0.f, 0.f};
    floatx4 acc[2][8];
    #pragma unroll
    for (int r = 0; r < 2; ++r)
      #pragma unroll
      for (int c = 0; c < 8; ++c) acc[r][c] = vz;

    #pragma unroll
    for (int kc = 0; kc < 2; ++kc) {               // x_t @ W_ih^T (K=64)
      const int koff = kc * 32 + quad * 8;
      bf16x8 a[2];
      #pragma unroll
      for (int r = 0; r < 2; ++r)
        a[r] = *(const bf16x8*)(xu +
                 (size_t)(n0 + r * 16 + mrow) * (T_STEPS * EMBD) + (size_t)t * EMBD + koff);
      #pragma unroll
      for (int ct = 0; ct < 8; ++ct) {
        const int g = colbase + ct * 16 + mrow;
        bf16x8 b = *(const bf16x8*)(Wi + (size_t)g * EMBD + koff);
        #pragma unroll
        for (int r = 0; r < 2; ++r)
          acc[r][ct] = __builtin_amdgcn_mfma_f32_16x16x32_bf16(a[r], b, acc[r][ct], 0, 0, 0);
      }
    }
    if (t > 0) {                                   // h @ W_hh^T (K=128)
      #pragma unroll
      for (int kc = 0; kc < 4; ++kc) {
        const int koff = kc * 32 + quad * 8;
        bf16x8 a[2];
        #pragma unroll
        for (int r = 0; r < 2; ++r)
          a[r] = *(const bf16x8*)(h_bf + (size_t)(n0 + r * 16 + mrow) * HD + koff);
        #pragma unroll
        for (int ct = 0; ct < 8; ++ct) {
          const int g = colbase + ct * 16 + mrow;
          bf16x8 b = *(const bf16x8*)(Wh + (size_t)g * HD + koff);
          #pragma unroll
          for (int r = 0; r < 2; ++r)
            acc[r][ct] = __builtin_amdgcn_mfma_f32_16x16x32_bf16(a[r], b, acc[r][ct], 0, 0, 0);
        }
      }
    }
    int lm[4], ln[4];
    #pragma unroll
    for (int reg = 0; reg < 4; ++reg) {
      const int v = lut32[lane * 4 + reg];
      lm[reg] = v >> 4; ln[reg] = v & 15;
    }
    #pragma unroll
    for (int r = 0; r < 2; ++r)
      #pragma unroll
      for (int ct = 0; ct < 8; ++ct)
        #pragma unroll
        for (int reg = 0; reg < 4; ++reg)
          gates[(r * 16 + lm[reg]) * G4 + colbase + ct * 16 + ln[reg]] = acc[r][ct][reg];
    __syncthreads();
  }
#if HAVE16
  else if (use16) {
    const bf16* xu = (const bf16*)x_user;
    const bf16* Wi = (const bf16*)W_ih;
    const bf16* Wh = (const bf16*)W_hh;
    const int wave = tid >> 6, lane = tid & 63;
    const int mrow = lane & 15, quad = lane >> 4;
    const int colbase = wave * 128;
    const floatx4 vz = {0.f, 0.f, 0.f, 0.f};
    floatx4 acc[2][8];
    #pragma unroll
    for (int r = 0; r < 2; ++r)
      #pragma unroll
      for (int c = 0; c < 8; ++c) acc[r][c] = vz;

    #pragma unroll
    for (int kc = 0; kc < 4; ++kc) {               // x_t @ W_ih^T, K=64 in 4 chunks
      const int koff = kc * 16 + quad * 4;
      short4v a[2];
      #pragma unroll
      for (int r = 0; r < 2; ++r)
        a[r] = *(const short4v*)(xu +
                 (size_t)(n0 + r * 16 + mrow) * (T_STEPS * EMBD) + (size_t)t * EMBD + koff);
      #pragma unroll
      for (int ct = 0; ct < 8; ++ct) {
        const int g = colbase + ct * 16 + mrow;
        short4v b = *(const short4v*)(Wi + (size_t)g * EMBD + koff);
        #pragma unroll
        for (int r = 0; r < 2; ++r)
          acc[r][ct] = __builtin_amdgcn_mfma_f32_16x16x16bf16_1k(a[r], b, acc[r][ct], 0, 0, 0);
      }
    }
    if (t > 0) {                                   // h @ W_hh^T, K=128 in 8 chunks
      #pragma unroll
      for (int kc = 0; kc < 8; ++kc) {
        const int koff = kc * 16 + quad * 4;
        short4v a[2];
        #pragma unroll
        for (int r = 0; r < 2; ++r)
          a[r] = *(const short4v*)(h_bf + (size_t)(n0 + r * 16 + mrow) * HD + koff);
        #pragma unroll
        for (int ct = 0; ct < 8; ++ct) {
          const int g = colbase + ct * 16 + mrow;
          short4v b = *(const short4v*)(Wh + (size_t)g * HD + koff);
          #pragma unroll
          for (int r = 0; r < 2; ++r)
            acc[r][ct] = __builtin_amdgcn_mfma_f32_16x16x16bf16_1k(a[r], b, acc[r][ct], 0, 0, 0);
        }
      }
    }
    int lm[4], ln[4];
    #pragma unroll
    for (int reg = 0; reg < 4; ++reg) {
      const int v = lut16[lane * 4 + reg];
      lm[reg] = v >> 4; ln[reg] = v & 15;
    }
    #pragma unroll
    for (int r = 0; r < 2; ++r)
      #pragma unroll
      for (int ct = 0; ct < 8; ++ct)
        #pragma unroll
        for (int reg = 0; reg < 4; ++reg)
          gates[(r * 16 + lm[reg]) * G4 + colbase + ct * 16 + ln[reg]] = acc[r][ct][reg];
    __syncthreads();
  }
#endif
  else {
    // -------- proven VALU GEMM fallback --------
    float* xl = smem;                        // 32x64
    float* hl = smem + 32 * EMBD;            // 32x128
    #pragma unroll
    for (int i = 0; i < 8; ++i) {
      const int idx = tid + i * 256;
      const int n = idx >> 6, k = idx & 63;
      xl[idx] = ldf(x_user, (size_t)(n0 + n) * (T_STEPS * EMBD) + (size_t)t * EMBD + k, isbf);
    }
    #pragma unroll
    for (int i = 0; i < 16; ++i) {
      const int idx = tid + i * 256;
      hl[idx] = (t == 0) ? 0.f : (float)h_bf[(size_t)n0 * HD + idx];
    }
    __syncthreads();
    const int col0 = tid, col1 = tid + 256;
    float acc0[32], acc1[32];
    #pragma unroll
    for (int n = 0; n < 32; ++n) { acc0[n] = 0.f; acc1[n] = 0.f; }
    for (int k = 0; k < EMBD; ++k) {
      const float w0 = ldf(W_ih, (size_t)col0 * EMBD + k, isbf);
      const float w1 = ldf(W_ih, (size_t)col1 * EMBD + k, isbf);
      #pragma unroll
      for (int n = 0; n < 32; ++n) {
        const float a = xl[n * EMBD + k];
        acc0[n] += a * w0; acc1[n] += a * w1;
      }
    }
    if (t > 0) {
      for (int k = 0; k < HD; ++k) {
        const float w0 = ldf(W_hh, (size_t)col0 * HD + k, isbf);
        const float w1 = ldf(W_hh, (size_t)col1 * HD + k, isbf);
        #pragma unroll
        for (int n = 0; n < 32; ++n) {
          const float a = hl[n * HD + k];
          acc0[n] += a * w0; acc1[n] += a * w1;
        }
      }
    }
    __syncthreads();
    #pragma unroll
    for (int n = 0; n < 32; ++n) {
      gates[n * G4 + col0] = acc0[n];
      gates[n * G4 + col1] = acc1[n];
    }
    __syncthreads();
  }

  // ---- cell update (gate order i,f,g,o) ----
  #pragma unroll
  for (int it = 0; it < 16; ++it) {
    const int lin = it * 256 + tid;
    const int nl = lin >> 7, j = lin & 127;
    const size_t n = (size_t)(n0 + nl);
    const float gi = gates[nl * G4 + j]       + ldf(b_ih, j, isbf)       + ldf(b_hh, j, isbf);
    const float gf = gates[nl * G4 + 128 + j] + ldf(b_ih, 128 + j, isbf) + ldf(b_hh, 128 + j, isbf);
    const float gg = gates[nl * G4 + 256 + j] + ldf(b_ih, 256 + j, isbf) + ldf(b_hh, 256 + j, isbf);
    const float go = gates[nl * G4 + 384 + j] + ldf(b_ih, 384 + j, isbf) + ldf(b_hh, 384 + j, isbf);
    const float iv = sigf(gi), fv = sigf(gf), gv = tanhf(gg), ov = sigf(go);
    const float cold = (t == 0) ? 0.f : cstate[n * HD + j];
    const float cnew = fv * cold + iv * gv;
    cstate[n * HD + j] = cnew;
    h_bf[n * HD + j] = (bf16)(ov * tanhf(cnew));
  }
}

// ---------------- content linear ----------------
__global__ __launch_bounds__(256) void k_content(
    const void* __restrict__ x_content, const void* __restrict__ Wc,
    const void* __restrict__ bc, bf16* __restrict__ c_out,
    const int* __restrict__ flagp)
{
  __shared__ float xl[32 * EMBD];
  const int isbf = *flagp;
  const int tid = threadIdx.x;
  const int n0 = blockIdx.x * 32;
  #pragma unroll
  for (int i = 0; i < 8; ++i) {
    const int idx = tid + i * 256;
    xl[idx] = ldf(x_content, (size_t)n0 * EMBD + idx, isbf);
  }
  __syncthreads();
  const int jj = tid & 127, grp = tid >> 7;
  float acc[16];
  #pragma unroll
  for (int nn = 0; nn < 16; ++nn) acc[nn] = 0.f;
  for (int k = 0; k < EMBD; ++k) {
    const float w = ldf(Wc, (size_t)jj * EMBD + k, isbf);
    #pragma unroll
    for (int nn = 0; nn < 16; ++nn)
      acc[nn] += xl[(grp * 16 + nn) * EMBD + k] * w;
  }
  const float bj = ldf(bc, jj, isbf);
  #pragma unroll
  for (int nn = 0; nn < 16; ++nn)
    c_out[(size_t)(n0 + grp * 16 + nn) * HD + jj] = (bf16)(acc[nn] + bj);
}

// ================= CSR build =================
__global__ void k_count_int(const int* __restrict__ src, const int* __restrict__ dst,
                            int* __restrict__ deg_u, int* __restrict__ deg_c, int E)
{
  const int e = blockIdx.x * blockDim.x + threadIdx.x;
  if (e < E) {
    atomicAdd(deg_u + (src[e] & NMASK), 1);
    atomicAdd(deg_c + (dst[e] & NMASK), 1);
  }
}

__global__ __launch_bounds__(256) void k_scan(const int* __restrict__ deg,
                                              int* __restrict__ row, int* __restrict__ cur)
{
  __shared__ int part[256];
  const int tid = threadIdx.x;
  const int base = tid * 128;
  int s = 0;
  for (int i = 0; i < 128; ++i) s += deg[base + i];
  part[tid] = s;
  __syncthreads();
  if (tid == 0) {
    int a = 0;
    for (int i = 0; i < 256; ++i) { const int v = part[i]; part[i] = a; a += v; }
  }
  __syncthreads();
  int a = part[tid];
  for (int i = 0; i < 128; ++i) {
    row[base + i] = a; cur[base + i] = a;
    a += deg[base + i];
  }
  if (tid == 255) row[N_NODES] = a;
}

__global__ void k_build(const int* __restrict__ src, const int* __restrict__ dst,
                        int* __restrict__ cur_u, int* __restrict__ cur_c,
                        int* __restrict__ adj_u, int* __restrict__ adj_c, int E)
{
  const int e = blockIdx.x * blockDim.x + threadIdx.x;
  if (e < E) {
    const int s = src[e] & NMASK, d = dst[e] & NMASK;
    const int pc = atomicAdd(cur_c + d, 1);
    adj_c[pc] = s;
    const int pu = atomicAdd(cur_u + s, 1);
    adj_u[pu] = d;
  }
}

// gather-sum: agg[n][:] = sum over adj rows of feat. One wave per node.
__global__ __launch_bounds__(256) void k_gather(
    const bf16* __restrict__ feat, const int* __restrict__ adj,
    const int* __restrict__ row, float* __restrict__ agg)
{
  const int node = blockIdx.x * 4 + (threadIdx.x >> 6);
  const int lane = threadIdx.x & 63;
  const int beg = row[node], end = row[node + 1];
  float a0 = 0.f, a1 = 0.f;
  for (int p = beg; p < end; ++p) {
    const int s = adj[p];
    const bf16x2 v = *(const bf16x2*)(feat + (size_t)s * HD + 2 * lane);
    a0 += (float)v.x; a1 += (float)v.y;
  }
  float2* o = (float2*)(agg + (size_t)node * HD + 2 * lane);
  *o = float2{a0, a1};
}

// ---------------- SAGE linear ----------------
__global__ __launch_bounds__(256) void k_sage_lin(
    const float* __restrict__ agg, const int* __restrict__ cnt,
    const bf16* __restrict__ dstx,
    const void* __restrict__ Wl, const void* __restrict__ bl,
    const void* __restrict__ Wr, bf16* __restrict__ outp,
    const int* __restrict__ flagp)
{
  __shared__ float ml[32 * HD];
  __shared__ float xl[32 * HD];
  const int isbf = *flagp;
  const int tid = threadIdx.x;
  const int n0 = blockIdx.x * 32;
  #pragma unroll
  for (int i = 0; i < 16; ++i) {
    const int idx = tid + i * 256;
    const int n = idx >> 7;
    const float rc = 1.f / fmaxf((float)cnt[n0 + n], 1.f);
    ml[idx] = agg[(size_t)n0 * HD + idx] * rc;
    xl[idx] = (float)dstx[(size_t)n0 * HD + idx];
  }
  __syncthreads();
  const int jj = tid & 127, grp = tid >> 7;
  float acc[16];
  #pragma unroll
  for (int nn = 0; nn < 16; ++nn) acc[nn] = 0.f;
  for (int k = 0; k < HD; ++k) {
    const float wl = ldf(Wl, (size_t)jj * HD + k, isbf);
    const float wr = ldf(Wr, (size_t)jj * HD + k, isbf);
    #pragma unroll
    for (int nn = 0; nn < 16; ++nn)
      acc[nn] += ml[(grp * 16 + nn) * HD + k] * wl + xl[(grp * 16 + nn) * HD + k] * wr;
  }
  const float bj = ldf(bl, jj, isbf);
  #pragma unroll
  for (int nn = 0; nn < 16; ++nn)
    outp[(size_t)(n0 + grp * 16 + nn) * HD + jj] = (bf16)fmaxf(acc[nn] + bj, 0.f);
}

// ---------------- classifier hidden ----------------
__global__ __launch_bounds__(256) void k_cls(
    const bf16* __restrict__ u, const bf16* __restrict__ c,
    const void* __restrict__ W1, const void* __restrict__ b1,
    float* __restrict__ h1, const int* __restrict__ flagp)
{
  __shared__ float ul[32 * HD];
  __shared__ float cl[32 * HD];
  const int isbf = *flagp;
  const int tid = threadIdx.x;
  const int n0 = blockIdx.x * 32;
  #pragma unroll
  for (int i = 0; i < 16; ++i) {
    const int idx = tid + i * 256;
    ul[idx] = (float)u[(size_t)n0 * HD + idx];
    cl[idx] = (float)c[(size_t)n0 * HD + idx];
  }
  __syncthreads();
  const int jj = tid & 127, grp = tid >> 7;
  float acc[16];
  #pragma unroll
  for (int nn = 0; nn < 16; ++nn) acc[nn] = 0.f;
  for (int k = 0; k < HD; ++k) {
    const float wu = ldf(W1, (size_t)jj * 256 + k, isbf);
    const float wc = ldf(W1, (size_t)jj * 256 + 128 + k, isbf);
    #pragma unroll
    for (int nn = 0; nn < 16; ++nn)
      acc[nn] += ul[(grp * 16 + nn) * HD + k] * wu + cl[(grp * 16 + nn) * HD + k] * wc;
  }
  const float bj = ldf(b1, jj, isbf);
  #pragma unroll
  for (int nn = 0; nn < 16; ++nn)
    h1[(size_t)(n0 + grp * 16 + nn) * HD + jj] = fmaxf(acc[nn] + bj, 0.f);
}

// ---------------- output ----------------
__global__ __launch_bounds__(256) void k_out(
    const float* __restrict__ h1, const void* __restrict__ W2,
    const void* __restrict__ b2, void* __restrict__ out,
    const int* __restrict__ flagp)
{
  const int isbf = *flagp;
  const int wave = threadIdx.x >> 6, lane = threadIdx.x & 63;
  const int n = blockIdx.x * 4 + wave;
  float v = h1[(size_t)n * HD + lane] * ldf(W2, lane, isbf)
          + h1[(size_t)n * HD + 64 + lane] * ldf(W2, 64 + lane, isbf);
  #pragma unroll
  for (int off = 32; off > 0; off >>= 1) v += __shfl_down(v, off, 64);
  if (lane == 0) {
    const float r = sigf(v + ldf(b2, 0, isbf));
    if (isbf) ((bf16*)out)[n] = (bf16)r; else ((float*)out)[n] = r;
  }
}

extern "C" void kernel_launch(void* const* d_in, const int* in_sizes, int n_in,
                              void* d_out, int out_size, void* d_ws, size_t ws_size,
                              hipStream_t stream)
{
  const void* x_user    = d_in[0];
  const void* x_content = d_in[1];
  const int*  edge      = (const int*)d_in[2];
  const void* W_ih      = d_in[3];
  const void* W_hh      = d_in[4];
  const void* b_ih      = d_in[5];
  const void* b_hh      = d_in[6];
  const void* Wc        = d_in[7];
  const void* bc        = d_in[8];
  const void* Wl[2]     = {d_in[9],  d_in[12]};
  const void* blv[2]    = {d_in[10], d_in[13]};
  const void* Wr[2]     = {d_in[11], d_in[14]};
  const void* W1        = d_in[15];
  const void* b1        = d_in[16];
  const void* W2        = d_in[17];
  const void* b2        = d_in[18];

  const int E = in_sizes[2] / 2;
  const int* src = edge;
  const int* dst = edge + E;

  // ---- workspace layout (< 60 MB; >=80 MB proven available) ----
  const size_t MB = 1u << 20;
  char* ws = (char*)d_ws;
  float* agg  = (float*)ws;                  // 16 MB fp32: cstate -> agg -> h1
  float* cst  = agg;
  float* h1   = agg;
  bf16* u0 = (bf16*)(ws + 16 * MB);          // 8 MB: LSTM h / u ping
  bf16* c0 = (bf16*)(ws + 24 * MB);          // 8 MB
  bf16* u1 = (bf16*)(ws + 32 * MB);          // 8 MB
  bf16* c1 = (bf16*)(ws + 40 * MB);          // 8 MB
  int*  adj_c = (int*)(ws + 48 * MB);        // 4 MB
  int*  adj_u = (int*)(ws + 52 * MB);        // 4 MB
  int*  meta  = (int*)(ws + 56 * MB);
  int* deg_u = meta;                         // 32768
  int* deg_c = deg_u + N_NODES;              // 32768
  int* row_u = deg_c + N_NODES;              // 32769
  int* row_c = row_u + N_NODES + 1;          // 32769
  int* cur_u = row_c + N_NODES + 1;          // 32768
  int* cur_c = cur_u + N_NODES;              // 32768
  int* flag  = cur_c + N_NODES;
  int* ok32  = flag + 1;
  int* ok16  = flag + 2;
  int* lut32 = flag + 4;                     // 256
  int* lut16 = lut32 + 256;                  // 256

  // ---- probes ----
  k_detect<<<1, 64, 0, stream>>>((const unsigned*)x_user, flag);
  k_probe<<<1, 64, 0, stream>>>(lut32, ok32, lut16, ok16);

  // ---- LSTM 20 steps ----
  for (int t = 0; t < T_STEPS; ++t)
    k_lstm_step<<<N_NODES / 32, 256, 0, stream>>>(x_user, W_ih, W_hh, b_ih, b_hh,
                                                  u0, cst, flag, ok32, ok16,
                                                  lut32, lut16, t);
  // ---- content embedding ----
  k_content<<<N_NODES / 32, 256, 0, stream>>>(x_content, Wc, bc, c0, flag);

  // ---- CSR build ----
  k_zero_int<<<(2 * N_NODES + 255) / 256, 256, 0, stream>>>(deg_u, 2 * N_NODES);
  k_count_int<<<(E + 255) / 256, 256, 0, stream>>>(src, dst, deg_u, deg_c, E);
  k_scan<<<1, 256, 0, stream>>>(deg_u, row_u, cur_u);
  k_scan<<<1, 256, 0, stream>>>(deg_c, row_c, cur_c);
  k_build<<<(E + 255) / 256, 256, 0, stream>>>(src, dst, cur_u, cur_c, adj_u, adj_c, E);

  // ---- 2 SAGE layers ----
  bf16* ui = u0; bf16* ci = c0; bf16* uo = u1; bf16* co = c1;
  for (int L = 0; L < 2; ++L) {
    k_gather<<<N_NODES / 4, 256, 0, stream>>>(ui, adj_c, row_c, agg);   // users -> content
    k_sage_lin<<<N_NODES / 32, 256, 0, stream>>>(agg, deg_c, ci, Wl[L], blv[L], Wr[L], co, flag);
    k_gather<<<N_NODES / 4, 256, 0, stream>>>(ci, adj_u, row_u, agg);   // content -> users
    k_sage_lin<<<N_NODES / 32, 256, 0, stream>>>(agg, deg_u, ui, Wl[L], blv[L], Wr[L], uo, flag);
    bf16* t1 = ui; ui = uo; uo = t1;
    bf16* t2 = ci; ci = co; co = t2;
  }

  // ---- classifier ----
  k_cls<<<N_NODES / 32, 256, 0, stream>>>(ui, ci, W1, b1, h1, flag);
  k_out<<<N_NODES / 4, 256, 0, stream>>>(h1, W2, b2, d_out, flag);
}